// Round 8
// baseline (506.919 us; speedup 1.0000x reference)
//
#include <hip/hip_runtime.h>
#include <hip/hip_bf16.h>

// All inputs and the output are fp32 (established empirically in rounds 1-2).
// Workspace layout is lifetime-aliased (high-water 56.5 MiB; see round-5 note).
//
// ROUND 13: k_tobasis1 take 4 -- supply the second block (k-split grid).
//   Round-12 cut LDS to 64 KB for 2 blocks/CU but grid was 256 = #CUs: only
//   ONE block per CU existed -> occupancy stuck at 19.5% (cap 25%), dur ~89us.
//   Resources permitted co-residency; the grid didn't supply it.
//   Fix: split basis-K: grid (NCH, 2, Bn) = 512 blocks, each 64k x 256c over
//   512 rows. x staging path byte-identical; ev path halves (evS 8K, evT 8K);
//   LDS 48 KB -> 3 blocks/CU capacity, 2 resident. evecs read once; x dup-read
//   L3-absorbed (x+evecs = 201 MB < 256 MB L3; round-0 vs round-7 FETCH both
//   98 MB confirms absorption). Waves: 2k x 4c regions, acc[2][4].
//   Predicted: tb1 ~50-58 us, occ ~40%, hbm ~30%.
//   History: tb1 95 (r7, 1blk/CU 149K LDS) -> 89 (r12, grid-capped);
//   attn (r8) ~45; fb2 (r9) 93 -> (r10) ~60.

#define Bn 4
#define Nn 32768
#define Kn 128
#define Cn 256
#define Mn 1024
#define Hn 8
#define Dn 32
#define NCH 64   // n-chunks for to_basis1 (chunk = 512 rows)
#define MCH 16   // m-chunks for to_basis2 (chunk = 64 rows)

typedef _Float16 f16;
typedef _Float16 f16x8 __attribute__((ext_vector_type(8)));
typedef float f32x4 __attribute__((ext_vector_type(4)));
typedef float f32x2 __attribute__((ext_vector_type(2)));
typedef unsigned int u32;
typedef unsigned int u32x4 __attribute__((ext_vector_type(4)));

__device__ __forceinline__ void gload_lds16(const float* g, float* l) {
    __builtin_amdgcn_global_load_lds(
        (const __attribute__((address_space(1))) void*)g,
        (__attribute__((address_space(3))) void*)l, 16, 0, 0);
}

static __device__ __forceinline__ u32 packf16(f16 a, f16 b) {
    union { f16 h[2]; u32 u; } x;
    x.h[0] = a; x.h[1] = b;
    return x.u;
}

// ---------------------------------------------------------------------------
// K1: to_basis #1 (f16x3 MFMA, k-split, 2 blocks/CU).
// part[b][nch][k0+k][c] = sum_{n in chunk} evecs[b,n,k0+k] * x[b,n,c]*mass[b,n]
// Grid (NCH, 2, Bn) = 512 blocks; 512 thr = 8 waves (2 k-qtrs x 4 c-qtrs);
// 16 strips of 32 rows. LDS 48 KB: evS 8 + evT 8 + xT 32.
// ---------------------------------------------------------------------------
__global__ __launch_bounds__(512, 4) void k_tobasis1(
    const float* __restrict__ x, const float* __restrict__ mass,
    const float* __restrict__ evecs, float* __restrict__ part)
{
    const int nch = blockIdx.x, ksp = blockIdx.y, b = blockIdx.z;
    const int n0 = nch * (Nn / NCH);
    const int k0 = ksp * 64;
    const int t = threadIdx.x;
    const int lane = t & 63, w = t >> 6;
    const int lr = lane & 15, lg = lane >> 4;
    const int wm = (w & 1) * 32;        // k-offset within the 64-row half
    const int wc = (w >> 1) * 64;       // c-offset

    __shared__ __align__(16) float evS[32][64];       //  8 KB fp32 scratch
    __shared__ __align__(16) f16 evT[64][64];         //  8 KB hi|lo, ^(k&7)
    __shared__ __align__(16) f16 xT[256][64];         // 32 KB hi|lo, ^((c>>3)&7)

    const size_t rb0 = (size_t)b * Nn + n0;
    const float* ebase = evecs + rb0 * Kn + k0;
    const float* xbase = x + rb0 * Cn;
    const float* mbase = mass + rb0;

    // x staging role: thread -> rows (2np, 2np+1), c-slice cc*8..+7
    const int cc = t & 31, np = t >> 5;

    f32x4 acc[2][4] = {};

    // prologue strip 0:
    // ev: wave w loads rows w*4..w*4+3 of the k-half (4 x 256B = 1 KB)
    gload_lds16(ebase + (size_t)(w * 4 + (lane >> 4)) * Kn + (lane & 15) * 4,
                &evS[0][0] + w * 256);
    f32x4 xa0, xa1, xb0, xb1;
    f32x2 mreg;
    {
        const float* xp = xbase + (size_t)(np * 2) * Cn + cc * 8;
        xa0 = *(const f32x4*)xp;       xa1 = *(const f32x4*)(xp + 4);
        xb0 = *(const f32x4*)(xp + Cn); xb1 = *(const f32x4*)(xp + Cn + 4);
        mreg = *(const f32x2*)(mbase + np * 2);
    }

    for (int s = 0; s < 16; s++) {
        // ev gload + x reg-loads for strip s all complete here.
        asm volatile("s_waitcnt vmcnt(0)" ::: "memory");
        __builtin_amdgcn_sched_barrier(0);
        __builtin_amdgcn_s_barrier();   // B1: tiles of s-1 fully read by all

        // transpose+split ev: evS -> evT (threads 0..255; ^(k&7) conflict-free)
        if (t < 256) {
            const int k = t & 63;
            const int g = t >> 6;          // 0..3, wave-uniform
            f16x8 hv, lv;
#pragma unroll
            for (int r = 0; r < 8; r++) {
                const float f = evS[g * 8 + r][k];
                const f16 h = (f16)f;
                hv[r] = h;
                lv[r] = (f16)(f - (float)h);
            }
            *(f16x8*)&evT[k][((g) ^ (k & 7)) * 8] = hv;
            *(f16x8*)&evT[k][((4 + g) ^ (k & 7)) * 8] = lv;
        }
        // convert x regs * mass -> xT transposed u32 n-pair writes
        {
            const float m0 = mreg[0], m1 = mreg[1];
            float r0[8] = {xa0[0]*m0, xa0[1]*m0, xa0[2]*m0, xa0[3]*m0,
                           xa1[0]*m0, xa1[1]*m0, xa1[2]*m0, xa1[3]*m0};
            float r1[8] = {xb0[0]*m1, xb0[1]*m1, xb0[2]*m1, xb0[3]*m1,
                           xb1[0]*m1, xb1[1]*m1, xb1[2]*m1, xb1[3]*m1};
#pragma unroll
            for (int j = 0; j < 8; j++) {
                const int c = cc * 8 + j;
                const int g = (c >> 3) & 7;
                const f16 h0 = (f16)r0[j], h1 = (f16)r1[j];
                const f16 l0 = (f16)(r0[j] - (float)h0), l1 = (f16)(r1[j] - (float)h1);
                u32* row = (u32*)&xT[c][0];
                row[((((np >> 2)    ) ^ g) << 2) | (np & 3)] = packf16(h0, h1);
                row[((((np >> 2) + 4) ^ g) << 2) | (np & 3)] = packf16(l0, l1);
            }
        }

        asm volatile("s_waitcnt lgkmcnt(0)" ::: "memory");
        __builtin_amdgcn_sched_barrier(0);
        __builtin_amdgcn_s_barrier();   // B2: tiles visible; evS fully consumed

        // stage strip s+1 (ev gload; x + mass into regs)
        if (s < 15) {
            const float* eb = ebase + (size_t)(s + 1) * 32 * Kn;
            gload_lds16(eb + (size_t)(w * 4 + (lane >> 4)) * Kn + (lane & 15) * 4,
                        &evS[0][0] + w * 256);
            const float* xp = xbase + (size_t)((s + 1) * 32 + np * 2) * Cn + cc * 8;
            xa0 = *(const f32x4*)xp;       xa1 = *(const f32x4*)(xp + 4);
            xb0 = *(const f32x4*)(xp + Cn); xb1 = *(const f32x4*)(xp + Cn + 4);
            mreg = *(const f32x2*)(mbase + (s + 1) * 32 + np * 2);
        }

        // frag reads + MFMA
        f16x8 aH[2], aL[2], bH[4], bL[4];
#pragma unroll
        for (int i = 0; i < 2; i++) {
            const int rk = wm + i * 16 + lr;
            aH[i] = *(const f16x8*)&evT[rk][((lg) ^ (rk & 7)) * 8];
            aL[i] = *(const f16x8*)&evT[rk][((4 + lg) ^ (rk & 7)) * 8];
        }
#pragma unroll
        for (int i = 0; i < 4; i++) {
            const int rc = wc + i * 16 + lr;
            const int gg = (rc >> 3) & 7;
            bH[i] = *(const f16x8*)&xT[rc][((lg) ^ gg) * 8];
            bL[i] = *(const f16x8*)&xT[rc][((4 + lg) ^ gg) * 8];
        }
#pragma unroll
        for (int i = 0; i < 2; i++)
#pragma unroll
            for (int j = 0; j < 4; j++) {
                acc[i][j] = __builtin_amdgcn_mfma_f32_16x16x32_f16(aH[i], bH[j], acc[i][j], 0, 0, 0);
                acc[i][j] = __builtin_amdgcn_mfma_f32_16x16x32_f16(aH[i], bL[j], acc[i][j], 0, 0, 0);
                acc[i][j] = __builtin_amdgcn_mfma_f32_16x16x32_f16(aL[i], bH[j], acc[i][j], 0, 0, 0);
            }
    }

    // epilogue: C/D layout col=lane&15, row=(lane>>4)*4+reg  [m89]
    float* dst = part + ((size_t)b * NCH + nch) * (Kn * Cn);
#pragma unroll
    for (int i = 0; i < 2; i++)
#pragma unroll
        for (int j = 0; j < 4; j++) {
            const int m0 = k0 + wm + i * 16 + lg * 4;
            const int c = wc + j * 16 + lr;
#pragma unroll
            for (int r = 0; r < 4; r++)
                dst[(size_t)(m0 + r) * Cn + c] = acc[i][j][r];
        }
}

// ---------------------------------------------------------------------------
// Reduce chunk partials and apply heat coefficient exp(-eval * t_c)
// ---------------------------------------------------------------------------
__global__ __launch_bounds__(256) void k_reduce(
    const float* __restrict__ part, int nchunks,
    const float* __restrict__ evals, const float* __restrict__ tvec,
    float* __restrict__ spec)
{
    const int b = blockIdx.x >> 7, k = blockIdx.x & 127, c = threadIdx.x;
    float ssum = 0.f;
    const float* p = part + ((size_t)b * nchunks * Kn + k) * Cn + c;
    for (int j = 0; j < nchunks; j++) ssum += p[(size_t)j * Kn * Cn];
    const float lam = evals[b * Kn + k];
    const float tt = fmaxf(tvec[c], 1e-8f);
    spec[((size_t)b * Kn + k) * Cn + c] = ssum * __expf(-lam * tt);
}

// ---------------------------------------------------------------------------
// Transpose+split spec2 fp32 [b][k][c] -> specT hi/lo f16 [b][c][k]
// ---------------------------------------------------------------------------
__global__ __launch_bounds__(256) void k_spectr(
    const float* __restrict__ spec, f16* __restrict__ sTh, f16* __restrict__ sTl)
{
    const int kc = blockIdx.x, b = blockIdx.y;
    const int t = threadIdx.x;
    __shared__ f16 lh[32][258];   // odd-dword rows -> conflict-free columns
    __shared__ f16 ll[32][258];
#pragma unroll 8
    for (int k2 = 0; k2 < 32; k2++) {
        const float f = spec[((size_t)b * Kn + kc * 32 + k2) * Cn + t];
        const f16 h = (f16)f;
        lh[k2][t] = h;
        ll[k2][t] = (f16)(f - (float)h);
    }
    __syncthreads();
    f16x8 vh[4], vl[4];
#pragma unroll
    for (int q = 0; q < 4; q++)
#pragma unroll
        for (int j = 0; j < 8; j++) { vh[q][j] = lh[q * 8 + j][t]; vl[q][j] = ll[q * 8 + j][t]; }
    f16* dh = sTh + ((size_t)b * 256 + t) * Kn + kc * 32;
    f16* dl = sTl + ((size_t)b * 256 + t) * Kn + kc * 32;
#pragma unroll
    for (int q = 0; q < 4; q++) {
        *(f16x8*)(dh + q * 8) = vh[q];
        *(f16x8*)(dl + q * 8) = vl[q];
    }
}

// ---------------------------------------------------------------------------
// Gather evecs & mass at far indices
// ---------------------------------------------------------------------------
__global__ __launch_bounds__(128) void k_gather(
    const float* __restrict__ evecs, const float* __restrict__ mass,
    const int* __restrict__ far, float* __restrict__ evf, float* __restrict__ massf)
{
    const int row = blockIdx.x;  // b*M + m
    const int b = row >> 10;
    const int idx = far[row];
    const int t = threadIdx.x;
    evf[(size_t)row * Kn + t] = evecs[((size_t)b * Nn + idx) * Kn + t];
    if (t == 0) massf[row] = mass[(size_t)b * Nn + idx];
}

// ---------------------------------------------------------------------------
// Generic 64x64-tile GEMM: out[row][c'] = X[row][0:KD] @ W[KD][256] (+bias)(*mass)
// ---------------------------------------------------------------------------
struct G3 {
    const float* W[3];
    const float* bias[3];
    float* out[3];
};

template<int KD, bool PERB, bool MMASS>
__global__ __launch_bounds__(256) void k_gemm64(
    const float* __restrict__ X, G3 g, const float* __restrict__ massf)
{
    const int mt = blockIdx.x, ct = blockIdx.y, z = blockIdx.z;
    const int row0 = mt * 64, c0 = ct * 64;
    const int b = row0 >> 10;
    const float* Wp = g.W[z];
    const float* bias = g.bias[z];
    float* out = g.out[z];
    const size_t woff = PERB ? (size_t)b * KD * 256 : 0;

    __shared__ float xT[32][68];   // 68*4 = 272 B rows (16B-aligned)
    __shared__ float wl[32][64];
    const int t = threadIdx.x, tx = t & 15, ty = t >> 4;
    float acc[4][4] = {};

    for (int k0 = 0; k0 < KD; k0 += 32) {
        {
            const int m = t >> 2, cc0 = (t & 3) * 8;
            const float* xs = X + (size_t)(row0 + m) * KD + k0 + cc0;
            float4 a0 = *(const float4*)xs, a1 = *(const float4*)(xs + 4);
            xT[cc0 + 0][m] = a0.x; xT[cc0 + 1][m] = a0.y; xT[cc0 + 2][m] = a0.z; xT[cc0 + 3][m] = a0.w;
            xT[cc0 + 4][m] = a1.x; xT[cc0 + 5][m] = a1.y; xT[cc0 + 6][m] = a1.z; xT[cc0 + 7][m] = a1.w;
        }
        {
            const int cc = t >> 3, col = (t & 7) * 8;
            const float* wsrc = Wp + woff + (size_t)(k0 + cc) * 256 + c0 + col;
            float4 a0 = *(const float4*)wsrc, a1 = *(const float4*)(wsrc + 4);
            wl[cc][col + 0] = a0.x; wl[cc][col + 1] = a0.y; wl[cc][col + 2] = a0.z; wl[cc][col + 3] = a0.w;
            wl[cc][col + 4] = a1.x; wl[cc][col + 5] = a1.y; wl[cc][col + 6] = a1.z; wl[cc][col + 7] = a1.w;
        }
        __syncthreads();
#pragma unroll 8
        for (int cc = 0; cc < 32; cc++) {
            float4 xv = *(const float4*)&xT[cc][ty * 4];
            float4 wv = *(const float4*)&wl[cc][tx * 4];
            float xa[4] = {xv.x, xv.y, xv.z, xv.w};
            float wa[4] = {wv.x, wv.y, wv.z, wv.w};
#pragma unroll
            for (int i = 0; i < 4; i++)
#pragma unroll
                for (int j = 0; j < 4; j++) acc[i][j] += xa[i] * wa[j];
        }
        __syncthreads();
    }
    float bj[4] = {0.f, 0.f, 0.f, 0.f};
    if (bias) {
#pragma unroll
        for (int j = 0; j < 4; j++) bj[j] = bias[c0 + tx * 4 + j];
    }
#pragma unroll
    for (int i = 0; i < 4; i++) {
        const int row = row0 + ty * 4 + i;
        const float mm = MMASS ? massf[row] : 1.f;
        *(float4*)(out + (size_t)row * 256 + c0 + tx * 4) =
            make_float4((acc[i][0] + bj[0]) * mm, (acc[i][1] + bj[1]) * mm,
                        (acc[i][2] + bj[2]) * mm, (acc[i][3] + bj[3]) * mm);
    }
}

// ---------------------------------------------------------------------------
// GroupNorm stats: per (b, g) mean/invstd over M x 8 channels
// ---------------------------------------------------------------------------
__global__ __launch_bounds__(256) void k_gnstats(const float* __restrict__ xfar, float* __restrict__ gst)
{
    const int b = blockIdx.x >> 5, g = blockIdx.x & 31;
    const int t = threadIdx.x;
    float s = 0.f, s2 = 0.f;
#pragma unroll
    for (int i = 0; i < 4; i++) {
        const int m = t * 4 + i;
        const float* p = xfar + ((size_t)b * Mn + m) * Cn + g * 8;
        float4 a = *(const float4*)p;
        float4 c = *(const float4*)(p + 4);
        s += a.x + a.y + a.z + a.w + c.x + c.y + c.z + c.w;
        s2 += a.x * a.x + a.y * a.y + a.z * a.z + a.w * a.w +
              c.x * c.x + c.y * c.y + c.z * c.z + c.w * c.w;
    }
    __shared__ float sb[256], sb2[256];
    sb[t] = s; sb2[t] = s2;
    __syncthreads();
    for (int o = 128; o > 0; o >>= 1) {
        if (t < o) { sb[t] += sb[t + o]; sb2[t] += sb2[t + o]; }
        __syncthreads();
    }
    if (t == 0) {
        const float mean = sb[0] * (1.f / 8192.f);
        const float var = sb2[0] * (1.f / 8192.f) - mean * mean;
        gst[2 * blockIdx.x] = mean;
        gst[2 * blockIdx.x + 1] = rsqrtf(var + 1e-6f);
    }
}

__global__ __launch_bounds__(256) void k_gnapply(
    const float* __restrict__ xfar, const float* __restrict__ gst,
    const float* __restrict__ gw, const float* __restrict__ gb, float* __restrict__ xn)
{
    const int idx = (blockIdx.x * 256 + threadIdx.x) * 4;
    const int c = idx & 255;
    const int row = idx >> 8;
    const int b = row >> 10;
    const int g = c >> 3;
    const float2 st = *(const float2*)&gst[2 * (b * 32 + g)];
    float4 vv = *(const float4*)&xfar[idx];
    float4 w4 = *(const float4*)&gw[c];
    float4 b4 = *(const float4*)&gb[c];
    float4 o;
    o.x = (vv.x - st.x) * st.y * w4.x + b4.x;
    o.y = (vv.y - st.x) * st.y * w4.y + b4.y;
    o.z = (vv.z - st.x) * st.y * w4.z + b4.z;
    o.w = (vv.w - st.x) * st.y * w4.w + b4.w;
    *(float4*)&xn[idx] = o;
}

// ---------------------------------------------------------------------------
// Flash attention, f16x3 MFMA, single pass over all 1024 keys.
// ---------------------------------------------------------------------------
__global__ __launch_bounds__(256) void k_attn(
    const float* __restrict__ q, const float* __restrict__ kbuf, const float* __restrict__ vbuf,
    float* __restrict__ att)
{
    const int qt = blockIdx.x;      // 16 tiles of 64 q-rows
    const int bh = blockIdx.y;      // b*8 + h
    const int b = bh >> 3, h = bh & 7;
    const int t = threadIdx.x;
    const int lane = t & 63, w = t >> 6;
    const int lr = lane & 15, lg = lane >> 4;

    __shared__ __align__(16) f16 Kh[64][32];     // [key][d] hi
    __shared__ __align__(16) f16 Kl[64][32];     // [key][d] lo
    __shared__ __align__(16) f16 Vh[32][64];     // [d][key] hi, 16B-chunk ^(d&7)
    __shared__ __align__(16) f16 Vl[32][64];     // [d][key] lo
    __shared__ __align__(16) u32 Pw[4][16][68];  // per-wave P (hi,lo) packed

    const size_t base = (size_t)b * Mn * Cn + h * Dn;
    const int q0 = qt * 64;

    f16x8 Qh, Ql;
    {
        const float* qp = q + base + (size_t)(q0 + w * 16 + lr) * Cn + lg * 8;
        f32x4 a0 = *(const f32x4*)qp;
        f32x4 a1 = *(const f32x4*)(qp + 4);
        const float scale = 0.17677669529663687f;
        float qv[8] = {a0[0], a0[1], a0[2], a0[3], a1[0], a1[1], a1[2], a1[3]};
#pragma unroll
        for (int r = 0; r < 8; r++) {
            const float f = qv[r] * scale;
            const f16 hh = (f16)f;
            Qh[r] = hh;
            Ql[r] = (f16)(f - (float)hh);
        }
    }

    const int krow = t >> 2, kdg = (t & 3) * 8;        // K: row, d-offset
    const int vrow = (t & 31) * 2, vdc = (t >> 5) * 4; // V: row-pair base, d-offset

    f32x4 kr0, kr1, va, vb;
    {
        const float* kp = kbuf + base + (size_t)krow * Cn + kdg;
        kr0 = *(const f32x4*)kp; kr1 = *(const f32x4*)(kp + 4);
        const float* vp = vbuf + base + (size_t)vrow * Cn + vdc;
        va = *(const f32x4*)vp; vb = *(const f32x4*)(vp + Cn);
    }

    float m_i[4], l_i[4];
    f32x4 acc[2] = {};
#pragma unroll
    for (int r = 0; r < 4; r++) { m_i[r] = -1e30f; l_i[r] = 0.f; }

#pragma unroll 1
    for (int kt = 0; kt < 16; kt++) {
        asm volatile("" ::: "memory");
        __builtin_amdgcn_s_barrier();   // all waves done reading K/V of tile kt-1

        {
            float kv[8] = {kr0[0], kr0[1], kr0[2], kr0[3], kr1[0], kr1[1], kr1[2], kr1[3]};
            f16x8 hv, lv;
#pragma unroll
            for (int r = 0; r < 8; r++) {
                const f16 hh = (f16)kv[r];
                hv[r] = hh;
                lv[r] = (f16)(kv[r] - (float)hh);
            }
            *(f16x8*)&Kh[krow][kdg] = hv;
            *(f16x8*)&Kl[krow][kdg] = lv;
        }
        {
            float v0[4] = {va[0], va[1], va[2], va[3]};
            float v1[4] = {vb[0], vb[1], vb[2], vb[3]};
#pragma unroll
            for (int j = 0; j < 4; j++) {
                const int d = vdc + j;
                const f16 h0 = (f16)v0[j], h1 = (f16)v1[j];
                const f16 l0 = (f16)(v0[j] - (float)h0), l1 = (f16)(v1[j] - (float)h1);
                const int col = vrow >> 1;                       // u32 col 0..31
                const int idx = (((col >> 2) ^ (d & 7)) << 2) | (col & 3);
                ((u32*)&Vh[d][0])[idx] = packf16(h0, h1);
                ((u32*)&Vl[d][0])[idx] = packf16(l0, l1);
            }
        }
        if (kt < 15) {
            const float* kp = kbuf + base + (size_t)((kt + 1) * 64 + krow) * Cn + kdg;
            kr0 = *(const f32x4*)kp; kr1 = *(const f32x4*)(kp + 4);
            const float* vp = vbuf + base + (size_t)((kt + 1) * 64 + vrow) * Cn + vdc;
            va = *(const f32x4*)vp; vb = *(const f32x4*)(vp + Cn);
        }

        asm volatile("s_waitcnt lgkmcnt(0)" ::: "memory");
        __builtin_amdgcn_sched_barrier(0);
        __builtin_amdgcn_s_barrier();   // K/V tile visible

        f32x4 s[4];
#pragma unroll
        for (int ct = 0; ct < 4; ct++) {
            const f16x8 khi = *(const f16x8*)&Kh[ct * 16 + lr][lg * 8];
            const f16x8 klo = *(const f16x8*)&Kl[ct * 16 + lr][lg * 8];
            f32x4 z = {};
            z = __builtin_amdgcn_mfma_f32_16x16x32_f16(Qh, khi, z, 0, 0, 0);
            z = __builtin_amdgcn_mfma_f32_16x16x32_f16(Qh, klo, z, 0, 0, 0);
            z = __builtin_amdgcn_mfma_f32_16x16x32_f16(Ql, khi, z, 0, 0, 0);
            s[ct] = z;
        }

        float tm[4];
#pragma unroll
        for (int r = 0; r < 4; r++)
            tm[r] = fmaxf(fmaxf(s[0][r], s[1][r]), fmaxf(s[2][r], s[3][r]));
#pragma unroll
        for (int r = 0; r < 4; r++) {
            tm[r] = fmaxf(tm[r], __shfl_xor(tm[r], 1));
            tm[r] = fmaxf(tm[r], __shfl_xor(tm[r], 2));
            tm[r] = fmaxf(tm[r], __shfl_xor(tm[r], 4));
            tm[r] = fmaxf(tm[r], __shfl_xor(tm[r], 8));
        }
        float corr[4], rs[4];
#pragma unroll
        for (int r = 0; r < 4; r++) {
            const float nm = fmaxf(m_i[r], tm[r]);
            corr[r] = __expf(m_i[r] - nm);
            m_i[r] = nm;
            rs[r] = 0.f;
        }
#pragma unroll
        for (int ct = 0; ct < 4; ct++)
#pragma unroll
            for (int r = 0; r < 4; r++) {
                const float p = __expf(s[ct][r] - m_i[r]);
                rs[r] += p;
                const f16 ph = (f16)p;
                const f16 pl = (f16)(p - (float)ph);
                Pw[w][lg * 4 + r][ct * 16 + lr] = packf16(ph, pl);
            }
#pragma unroll
        for (int r = 0; r < 4; r++) {
            rs[r] += __shfl_xor(rs[r], 1);
            rs[r] += __shfl_xor(rs[r], 2);
            rs[r] += __shfl_xor(rs[r], 4);
            rs[r] += __shfl_xor(rs[r], 8);
            l_i[r] = l_i[r] * corr[r] + rs[r];
        }
#pragma unroll
        for (int dt = 0; dt < 2; dt++)
#pragma unroll
            for (int r = 0; r < 4; r++) acc[dt][r] *= corr[r];

        asm volatile("s_waitcnt lgkmcnt(0)" ::: "memory");
        __builtin_amdgcn_sched_barrier(0);

        f16x8 pah[2], pal[2];
#pragma unroll
        for (int kc = 0; kc < 2; kc++) {
            const u32* prow = &Pw[w][lr][0] + kc * 32 + lg * 8;
            u32x4 ua = *(const u32x4*)prow;
            u32x4 ub = *(const u32x4*)(prow + 4);
            union { u32 wd[4]; f16x8 v; } hh, ll;
            hh.wd[0] = __builtin_amdgcn_perm(ua[1], ua[0], 0x05040100u);
            hh.wd[1] = __builtin_amdgcn_perm(ua[3], ua[2], 0x05040100u);
            hh.wd[2] = __builtin_amdgcn_perm(ub[1], ub[0], 0x05040100u);
            hh.wd[3] = __builtin_amdgcn_perm(ub[3], ub[2], 0x05040100u);
            ll.wd[0] = __builtin_amdgcn_perm(ua[1], ua[0], 0x07060302u);
            ll.wd[1] = __builtin_amdgcn_perm(ua[3], ua[2], 0x07060302u);
            ll.wd[2] = __builtin_amdgcn_perm(ub[1], ub[0], 0x07060302u);
            ll.wd[3] = __builtin_amdgcn_perm(ub[3], ub[2], 0x07060302u);
            pah[kc] = hh.v;
            pal[kc] = ll.v;
        }

#pragma unroll
        for (int dt = 0; dt < 2; dt++)
#pragma unroll
            for (int kc = 0; kc < 2; kc++) {
                const int d = dt * 16 + lr;
                const int ch = ((kc * 4 + lg) ^ (lr & 7)) * 8;
                const f16x8 vh = *(const f16x8*)&Vh[d][ch];
                const f16x8 vl = *(const f16x8*)&Vl[d][ch];
                acc[dt] = __builtin_amdgcn_mfma_f32_16x16x32_f16(pah[kc], vh, acc[dt], 0, 0, 0);
                acc[dt] = __builtin_amdgcn_mfma_f32_16x16x32_f16(pah[kc], vl, acc[dt], 0, 0, 0);
                acc[dt] = __builtin_amdgcn_mfma_f32_16x16x32_f16(pal[kc], vh, acc[dt], 0, 0, 0);
            }
    }

#pragma unroll
    for (int r = 0; r < 4; r++) {
        const float inv = 1.f / l_i[r];
        const size_t orow = (size_t)b * Mn + q0 + w * 16 + lg * 4 + r;
#pragma unroll
        for (int dt = 0; dt < 2; dt++)
            att[orow * Cn + h * Dn + dt * 16 + lr] = acc[dt][r] * inv;
    }
}

// ---------------------------------------------------------------------------
// to_basis #2 over far rows only
// ---------------------------------------------------------------------------
__global__ __launch_bounds__(256) void k_tobasis2(
    const float* __restrict__ evf, const float* __restrict__ xo, float* __restrict__ part)
{
    const int mch = blockIdx.x, ct = blockIdx.y, b = blockIdx.z;
    const int m0 = mch * (Mn / MCH);
    const int c0 = ct * 128;
    __shared__ float ev[32][128];
    __shared__ float xm[32][128];
    const int t = threadIdx.x, tx = t & 15, ty = t >> 4;
    float acc[8][8];
#pragma unroll
    for (int i = 0; i < 8; i++)
#pragma unroll
        for (int j = 0; j < 8; j++) acc[i][j] = 0.f;
    const int lr = t >> 3, lc = (t & 7) * 16;
    for (int s = 0; s < Mn / MCH; s += 32) {
        const size_t mrow = (size_t)b * Mn + m0 + s + lr;
        {
            const float* es = evf + mrow * Kn + lc;
            *(float4*)&ev[lr][lc]      = *(const float4*)es;
            *(float4*)&ev[lr][lc + 4]  = *(const float4*)(es + 4);
            *(float4*)&ev[lr][lc + 8]  = *(const float4*)(es + 8);
            *(float4*)&ev[lr][lc + 12] = *(const float4*)(es + 12);
            const float* xs = xo + mrow * Cn + c0 + lc;
            *(float4*)&xm[lr][lc]      = *(const float4*)xs;
            *(float4*)&xm[lr][lc + 4]  = *(const float4*)(xs + 4);
            *(float4*)&xm[lr][lc + 8]  = *(const float4*)(xs + 8);
            *(float4*)&xm[lr][lc + 12] = *(const float4*)(xs + 12);
        }
        __syncthreads();
#pragma unroll 4
        for (int nn = 0; nn < 32; nn++) {
            float4 e0 = *(const float4*)&ev[nn][ty * 4];
            float4 e1 = *(const float4*)&ev[nn][64 + ty * 4];
            float4 x0 = *(const float4*)&xm[nn][tx * 4];
            float4 x1 = *(const float4*)&xm[nn][64 + tx * 4];
            float ee[8] = {e0.x, e0.y, e0.z, e0.w, e1.x, e1.y, e1.z, e1.w};
            float xx[8] = {x0.x, x0.y, x0.z, x0.w, x1.x, x1.y, x1.z, x1.w};
#pragma unroll
            for (int i = 0; i < 8; i++)
#pragma unroll
                for (int j = 0; j < 8; j++) acc[i][j] += ee[i] * xx[j];
        }
        __syncthreads();
    }
    float* dst = part + ((size_t)b * MCH + mch) * (Kn * Cn);
#pragma unroll
    for (int i = 0; i < 8; i++) {
        const int k = (i < 4) ? (ty * 4 + i) : (64 + ty * 4 + i - 4);
        *(float4*)(dst + (size_t)k * Cn + c0 + tx * 4) =
            make_float4(acc[i][0], acc[i][1], acc[i][2], acc[i][3]);
        *(float4*)(dst + (size_t)k * Cn + c0 + 64 + tx * 4) =
            make_float4(acc[i][4], acc[i][5], acc[i][6], acc[i][7]);
    }
}

// ---------------------------------------------------------------------------
// from_basis #2 (f16x3 MFMA, pipelined LDS staging):
// out[b,n,c] = ow[c] * sum_k evecs[b,n,k] * spec2[b,k,c]
// ---------------------------------------------------------------------------
__global__ __launch_bounds__(512) void k_frombasis2(
    const float* __restrict__ evecs, const f16* __restrict__ sTh,
    const f16* __restrict__ sTl, const float* __restrict__ outw,
    float* __restrict__ out)
{
    const int nt = blockIdx.x, b = blockIdx.z;
    const int n0 = nt * 128;
    const int t = threadIdx.x;
    const int lane = t & 63, w = t >> 6;
    const int lr = lane & 15, lg = lane >> 4;
    const int wn = (w & 1) * 64;        // n-offset within block
    const int wc = (w >> 1) * 64;       // c-offset

    __shared__ __align__(16) f16 aT[2][128][64];   // 32 KB, hi|lo interleaved

    const int srow = t >> 2;        // 0..127
    const int skc = t & 3;          // 0..3
    const float* Abase = evecs + ((size_t)b * Nn + n0 + srow) * Kn + skc * 8;

    const f16* Bh = sTh + ((size_t)b * 256 + wc + lr) * Kn + lg * 8;
    const f16* Bl = sTl + ((size_t)b * 256 + wc + lr) * Kn + lg * 8;

    f32x4 acc[4][4] = {};

    f32x4 a0 = *(const f32x4*)(Abase);
    f32x4 a1 = *(const f32x4*)(Abase + 4);

#pragma unroll 1
    for (int kk = 0; kk < 4; kk++) {
        const int p = kk & 1;
        {
            float av[8] = {a0[0], a0[1], a0[2], a0[3], a1[0], a1[1], a1[2], a1[3]};
            f16x8 hv, lv;
#pragma unroll
            for (int r = 0; r < 8; r++) {
                const float f = av[r] * 256.f;   // exact scale: lo stays normal
                const f16 hh = (f16)f;
                hv[r] = hh;
                lv[r] = (f16)(f - (float)hh);
            }
            *(f16x8*)&aT[p][srow][((skc) ^ (srow & 7)) * 8] = hv;
            *(f16x8*)&aT[p][srow][((4 + skc) ^ (srow & 7)) * 8] = lv;
        }
        if (kk < 3) {
            a0 = *(const f32x4*)(Abase + (kk + 1) * 32);
            a1 = *(const f32x4*)(Abase + (kk + 1) * 32 + 4);
        }
        f16x8 bh[4], bl[4];
#pragma unroll
        for (int cf = 0; cf < 4; cf++) {
            bh[cf] = *(const f16x8*)(Bh + (size_t)cf * 16 * Kn + kk * 32);
            bl[cf] = *(const f16x8*)(Bl + (size_t)cf * 16 * Kn + kk * 32);
        }

        asm volatile("s_waitcnt lgkmcnt(0)" ::: "memory");
        __builtin_amdgcn_sched_barrier(0);
        __builtin_amdgcn_s_barrier();   // aT[p] visible to all waves

#pragma unroll
        for (int rf = 0; rf < 4; rf++) {
            const int rn = wn + rf * 16 + lr;
            const f16x8 ah = *(const f16x8*)&aT[p][rn][((lg) ^ (rn & 7)) * 8];
            const f16x8 al = *(const f16x8*)&aT[p][rn][((4 + lg) ^ (rn & 7)) * 8];
#pragma unroll
            for (int cf = 0; cf < 4; cf++) {
                acc[rf][cf] = __builtin_amdgcn_mfma_f32_16x16x32_f16(ah, bh[cf], acc[rf][cf], 0, 0, 0);
                acc[rf][cf] = __builtin_amdgcn_mfma_f32_16x16x32_f16(ah, bl[cf], acc[rf][cf], 0, 0, 0);
                acc[rf][cf] = __builtin_amdgcn_mfma_f32_16x16x32_f16(al, bh[cf], acc[rf][cf], 0, 0, 0);
            }
        }
    }

    float ow4[4];
#pragma unroll
    for (int cf = 0; cf < 4; cf++)
        ow4[cf] = fmaxf(outw[wc + cf * 16 + lr], 1e-8f) * (1.f / 256.f);
#pragma unroll
    for (int rf = 0; rf < 4; rf++)
#pragma unroll
        for (int cf = 0; cf < 4; cf++) {
            const int nn = n0 + wn + rf * 16 + lg * 4;
            const int c = wc + cf * 16 + lr;
#pragma unroll
            for (int r = 0; r < 4; r++)
                out[((size_t)b * Nn + nn + r) * Cn + c] = acc[rf][cf][r] * ow4[cf];
        }
}

// ---------------------------------------------------------------------------
extern "C" void kernel_launch(void* const* d_in, const int* in_sizes, int n_in,
                              void* d_out, int out_size, void* d_ws, size_t ws_size,
                              hipStream_t stream)
{
    const float* x     = (const float*)d_in[0];
    const float* mass  = (const float*)d_in[1];
    const float* evals = (const float*)d_in[2];
    const float* evecs = (const float*)d_in[3];
    const int*   far   = (const int*)d_in[4];
    const float* t_in  = (const float*)d_in[5];
    const float* t_out = (const float*)d_in[6];
    const float* gn_w  = (const float*)d_in[7];
    const float* gn_b  = (const float*)d_in[8];
    const float* Wq    = (const float*)d_in[9];
    const float* bq    = (const float*)d_in[10];
    const float* Wk    = (const float*)d_in[11];
    const float* bk    = (const float*)d_in[12];
    const float* Wv    = (const float*)d_in[13];
    const float* bv    = (const float*)d_in[14];
    const float* Wo    = (const float*)d_in[15];
    const float* bo    = (const float*)d_in[16];
    const float* outw  = (const float*)d_in[17];
    float* out = (float*)d_out;
    float* ws = (float*)d_ws;

    // --- Lifetime-aliased workspace layout (same offsets as rounds 5-12).
    float* A     = ws;                      // 8,388,608
    float* evf   = ws    + 8388608;         //   524,288 (k3..k10)
    float* massf = evf   + 524288;          //     4,096
    float* gst   = massf + 4096;            //       256
    float* pm    = gst   + 256;             //   262,144 (-> specT planes)
    float* pl    = pm    + 262144;          //   262,144 (unused)
    float* spec1 = pl    + 262144;          //   131,072
    float* xfar  = spec1 + 131072;          // 1,048,576
    float* xn    = xfar  + 1048576;         // 1,048,576
    float* q     = xn    + 1048576;         // 1,048,576
    float* kk    = q     + 1048576;         // 1,048,576
    float* v     = kk    + 1048576;         // 1,048,576  (ends at 14,815,488)
    float* part2 = A;
    float* spec2 = spec1;   // spec1 dead after from_basis1
    float* xo    = xfar;    // xfar dead after gnapply
    float* att   = xn;      // xn dead after QKV gemm
    f16* specTh  = (f16*)pm;            // 131072 f16 = 256 KB
    f16* specTl  = specTh + 131072;     // 131072 f16 = 256 KB (fits pm slot)
    (void)pl;

    k_tobasis1<<<dim3(NCH, 2, Bn), 512, 0, stream>>>(x, mass, evecs, A);
    k_reduce<<<Bn * Kn, Cn, 0, stream>>>(A, NCH, evals, t_in, spec1);
    k_gather<<<Bn * Mn, Kn, 0, stream>>>(evecs, mass, far, evf, massf);
    {
        G3 g{};
        g.W[0] = spec1; g.bias[0] = nullptr; g.out[0] = xfar;
        k_gemm64<128, true, false><<<dim3(64, 4, 1), 256, 0, stream>>>(evf, g, nullptr);
    }
    k_gnstats<<<Bn * 32, 256, 0, stream>>>(xfar, gst);
    k_gnapply<<<1024, 256, 0, stream>>>(xfar, gst, gn_w, gn_b, xn);
    {
        G3 g{};
        g.W[0] = Wq; g.W[1] = Wk; g.W[2] = Wv;
        g.bias[0] = bq; g.bias[1] = bk; g.bias[2] = bv;
        g.out[0] = q; g.out[1] = kk; g.out[2] = v;
        k_gemm64<256, false, false><<<dim3(64, 4, 3), 256, 0, stream>>>(xn, g, nullptr);
    }
    k_attn<<<dim3(16, 32), 256, 0, stream>>>(q, kk, v, att);
    {
        G3 g{};
        g.W[0] = Wo; g.bias[0] = bo; g.out[0] = xo;
        k_gemm64<256, false, true><<<dim3(64, 4, 1), 256, 0, stream>>>(att, g, massf);
    }
    k_tobasis2<<<dim3(MCH, 2, Bn), 256, 0, stream>>>(evf, xo, part2);
    k_reduce<<<Bn * Kn, Cn, 0, stream>>>(part2, MCH, evals, t_out, spec2);
    k_spectr<<<dim3(4, Bn), 256, 0, stream>>>(spec2, specTh, specTl);
    k_frombasis2<<<dim3(256, 1, Bn), 512, 0, stream>>>(evecs, specTh, specTl, outw, out);
}